// Round 1
// baseline (1404.916 us; speedup 1.0000x reference)
//
#include <hip/hip_runtime.h>

#define BB 512
#define TT 512
#define EE 64
#define HH 64
#define KK 9
#define ZDIM 256  // 4*H

__device__ __forceinline__ float sigm(float x) { return 1.0f / (1.0f + __expf(-x)); }
__device__ __forceinline__ float tanh_(float x) { return 1.0f - 2.0f / (__expf(2.0f * x) + 1.0f); }

// One workgroup = 2 waves = one (row, direction) chain.
// wave 0: producer, holds W (E x 256) in VGPRs, computes zx = x_t @ W one step ahead.
// wave 1: consumer, holds U (H x 256) + Wd column in VGPRs, computes z = zx + h@U + b,
//         gates, state update, and the direction's 9-dim potential contribution.
// Gate layout permuted so lane u owns z[{i,f,g,o}][u] -> unit u entirely within lane u.
__global__ __launch_bounds__(128, 1)
void lstm_kernel(const int* __restrict__ tokens,
                 const float* __restrict__ emb,
                 const float* __restrict__ Wf, const float* __restrict__ Uf, const float* __restrict__ bf,
                 const float* __restrict__ Wb, const float* __restrict__ Ub, const float* __restrict__ bbias,
                 const float* __restrict__ Wd,
                 float* __restrict__ potf, float* __restrict__ potb)
{
    const int bid  = blockIdx.x;
    const int dir  = bid >> 9;     // 0 = forward, 1 = backward
    const int row  = bid & 511;
    const int lane = threadIdx.x & 63;
    const int wave = threadIdx.x >> 6;

    const float* Wp = dir ? Wb : Wf;
    const float* Up = dir ? Ub : Uf;
    const float* bp = dir ? bbias : bf;
    float* pot      = dir ? potb : potf;

    __shared__ __align__(16) float zxbuf[2][ZDIM];
    __shared__ __align__(16) float hbuf[2][HH];

    const int* trow = tokens + row * TT;

    if (wave == 0) {
        // ---------------- producer ----------------
        float wreg[EE][4];
#pragma unroll
        for (int k = 0; k < EE; ++k)
#pragma unroll
            for (int g = 0; g < 4; ++g)
                wreg[k][g] = Wp[k * ZDIM + g * HH + lane];

        // prologue: zx for s=0 into buffer 0
        {
            const int t = dir ? (TT - 1) : 0;
            int tok = __builtin_amdgcn_readfirstlane(trow[t]);
            const float* xr = emb + (long)tok * EE;
            float a0 = 0.f, a1 = 0.f, a2 = 0.f, a3 = 0.f;
#pragma unroll
            for (int k = 0; k < EE; ++k) {
                float xk = xr[k];
                a0 += xk * wreg[k][0]; a1 += xk * wreg[k][1];
                a2 += xk * wreg[k][2]; a3 += xk * wreg[k][3];
            }
            *((float4*)&zxbuf[0][lane * 4]) = make_float4(a0, a1, a2, a3);
        }
        __syncthreads();
        for (int s = 0; s < TT; ++s) {
            if (s + 1 < TT) {
                const int t = dir ? (TT - 2 - s) : (s + 1);
                int tok = __builtin_amdgcn_readfirstlane(trow[t]);
                const float* xr = emb + (long)tok * EE;
                float a0 = 0.f, a1 = 0.f, a2 = 0.f, a3 = 0.f;
#pragma unroll
                for (int k = 0; k < EE; ++k) {
                    float xk = xr[k];
                    a0 += xk * wreg[k][0]; a1 += xk * wreg[k][1];
                    a2 += xk * wreg[k][2]; a3 += xk * wreg[k][3];
                }
                *((float4*)&zxbuf[(s + 1) & 1][lane * 4]) = make_float4(a0, a1, a2, a3);
            }
            __syncthreads();
        }
    } else {
        // ---------------- consumer ----------------
        float ureg[HH][4];
#pragma unroll
        for (int k = 0; k < HH; ++k)
#pragma unroll
            for (int g = 0; g < 4; ++g)
                ureg[k][g] = Up[k * ZDIM + g * HH + lane];

        float breg[4];
#pragma unroll
        for (int g = 0; g < 4; ++g) breg[g] = bp[g * HH + lane];

        float wdreg[HH];
#pragma unroll
        for (int u = 0; u < HH; ++u)
            wdreg[u] = (lane < KK) ? Wd[(dir ? (HH + u) : u) * KK + lane] : 0.f;

        float c = 0.f, hprev = 0.f;
        __syncthreads();
        for (int s = 0; s < TT; ++s) {
            const int t = dir ? (TT - 1 - s) : s;
            const int tokt = trow[t];
            float4 zv = *((const float4*)&zxbuf[s & 1][lane * 4]);
            float zh[4] = {0.f, 0.f, 0.f, 0.f};
            float pp = 0.f;
            if (s > 0) {
                const float* hb_ = hbuf[s & 1];
#pragma unroll
                for (int k4 = 0; k4 < HH / 4; ++k4) {
                    float4 hv = *((const float4*)&hb_[k4 * 4]);
                    float he[4] = {hv.x, hv.y, hv.z, hv.w};
#pragma unroll
                    for (int e = 0; e < 4; ++e) {
                        const int k = 4 * k4 + e;
#pragma unroll
                        for (int g = 0; g < 4; ++g) zh[g] += he[e] * ureg[k][g];
                        if (lane < KK) pp += he[e] * wdreg[k];
                    }
                }
                const int tprev = dir ? (TT - s) : (s - 1);
                if (lane < KK)
                    pot[((long)row * TT + tprev) * KK + lane] = pp;
            }
            float zi = zv.x + zh[0] + breg[0];
            float zf = zv.y + zh[1] + breg[1];
            float zg = zv.z + zh[2] + breg[2];
            float zo = zv.w + zh[3] + breg[3];
            float cn = sigm(zf) * c + sigm(zi) * tanh_(zg);
            float hn = sigm(zo) * tanh_(cn);
            bool m = (tokt != 0);
            float h2 = m ? hn : hprev;
            c = m ? cn : c;
            hprev = h2;
            hbuf[(s + 1) & 1][lane] = h2;
            __syncthreads();
        }
        // epilogue: potential for the last processed position, h state in hbuf[TT&1]=hbuf[0]
        {
            const int tlast = dir ? 0 : (TT - 1);
            if (lane < KK) {
                const float* hb_ = hbuf[0];
                float pp = 0.f;
#pragma unroll
                for (int u = 0; u < HH; ++u) pp += hb_[u] * wdreg[u];
                pot[((long)row * TT + tlast) * KK + lane] = pp;
            }
        }
    }
}

__global__ void combine_kernel(const float* __restrict__ potf, const float* __restrict__ potb,
                               const float* __restrict__ bd, float* __restrict__ pot_out)
{
    int idx = blockIdx.x * blockDim.x + threadIdx.x;
    const int total = BB * TT * KK;
    if (idx < total) {
        int k = idx % KK;
        pot_out[idx] = potf[idx] + potb[idx] + bd[k];
    }
}

__global__ __launch_bounds__(64)
void viterbi_kernel(const int* __restrict__ tokens, const float* __restrict__ pot,
                    const float* __restrict__ trans, float* __restrict__ dec_out,
                    float* __restrict__ seq_out)
{
    const int row  = blockIdx.x;
    const int lane = threadIdx.x;

    __shared__ unsigned char bpl[(TT - 1) * KK];
    __shared__ unsigned char maskl[TT];
    __shared__ float decl_[TT];

    const int* trow = tokens + row * TT;

    int cnt = 0;
#pragma unroll
    for (int ch = 0; ch < TT / 64; ++ch) {
        int tk = trow[ch * 64 + lane];
        int m = (tk != 0) ? 1 : 0;
        maskl[ch * 64 + lane] = (unsigned char)m;
        cnt += m;
    }
    for (int off = 32; off > 0; off >>= 1) cnt += __shfl_down(cnt, off);
    if (lane == 0) seq_out[row] = (float)cnt;
    __syncthreads();

    float treg[KK];
#pragma unroll
    for (int i = 0; i < KK; ++i)
        treg[i] = (lane < KK) ? trans[i * KK + lane] : 0.f;

    const float* prow = pot + (long)row * TT * KK;
    float alpha = (lane < KK) ? prow[lane] : -1e30f;

    for (int t = 1; t < TT; ++t) {
        float p = (lane < KK) ? prow[t * KK + lane] : 0.f;
        float best = -1e30f; int arg = 0;
#pragma unroll
        for (int i = 0; i < KK; ++i) {
            float sc = __shfl(alpha, i) + treg[i];
            if (sc > best) { best = sc; arg = i; }   // strict > keeps first max (np.argmax)
        }
        bool m = maskl[t] != 0;
        float anew = m ? (best + p) : alpha;
        int bpv = m ? arg : lane;
        alpha = anew;
        if (lane < KK) bpl[(t - 1) * KK + lane] = (unsigned char)bpv;
    }

    // final argmax over alpha (all lanes compute, first-max tie rule)
    float bestA = -1e30f; int last = 0;
#pragma unroll
    for (int i = 0; i < KK; ++i) {
        float ai = __shfl(alpha, i);
        if (ai > bestA) { bestA = ai; last = i; }
    }
    __syncthreads();

    if (lane == 0) {
        int tag = last;
        decl_[TT - 1] = maskl[TT - 1] ? (float)tag : 0.f;
        for (int t = TT - 2; t >= 0; --t) {
            tag = bpl[t * KK + tag];
            decl_[t] = maskl[t] ? (float)tag : 0.f;
        }
    }
    __syncthreads();

    float* drow = dec_out + (long)row * TT;
#pragma unroll
    for (int ch = 0; ch < TT / 64; ++ch)
        drow[ch * 64 + lane] = decl_[ch * 64 + lane];
}

extern "C" void kernel_launch(void* const* d_in, const int* in_sizes, int n_in,
                              void* d_out, int out_size, void* d_ws, size_t ws_size,
                              hipStream_t stream)
{
    const int*   tokens = (const int*)d_in[0];
    const float* emb    = (const float*)d_in[1];
    const float* Wf     = (const float*)d_in[2];
    const float* Uf     = (const float*)d_in[3];
    const float* bf     = (const float*)d_in[4];
    const float* Wb     = (const float*)d_in[5];
    const float* Ub     = (const float*)d_in[6];
    const float* bb     = (const float*)d_in[7];
    const float* Wd     = (const float*)d_in[8];
    const float* bd     = (const float*)d_in[9];
    const float* trans  = (const float*)d_in[10];

    float* out     = (float*)d_out;
    float* dec_out = out;                                    // B*T
    float* pot_out = out + (long)BB * TT;                    // B*T*K
    float* seq_out = out + (long)BB * TT + (long)BB * TT * KK; // B

    float* potf = (float*)d_ws;
    float* potb = potf + (long)BB * TT * KK;

    hipLaunchKernelGGL(lstm_kernel, dim3(1024), dim3(128), 0, stream,
                       tokens, emb, Wf, Uf, bf, Wb, Ub, bb, Wd, potf, potb);

    const int total = BB * TT * KK;
    hipLaunchKernelGGL(combine_kernel, dim3((total + 255) / 256), dim3(256), 0, stream,
                       potf, potb, bd, pot_out);

    hipLaunchKernelGGL(viterbi_kernel, dim3(BB), dim3(64), 0, stream,
                       tokens, pot_out, trans, dec_out, seq_out);
}